// Round 11
// baseline (2150.637 us; speedup 1.0000x reference)
//
#include <hip/hip_runtime.h>
#include <hip/hip_fp16.h>

namespace {

constexpr int kS = 1024;   // SEQ
constexpr int kI = 64;     // INPUT_SIZE
constexpr int kH = 128;    // HIDDEN

typedef _Float16 f16x8 __attribute__((ext_vector_type(8)));
typedef float    f32x4 __attribute__((ext_vector_type(4)));

#define MFMA16(a, b, c) __builtin_amdgcn_mfma_f32_16x16x32_f16((a), (b), (c), 0, 0, 0)

__device__ __forceinline__ float rcpf(float x) {
#if __has_builtin(__builtin_amdgcn_rcpf)
  return __builtin_amdgcn_rcpf(x);
#else
  return 1.0f / x;
#endif
}
__device__ __forceinline__ float sigf(float x)  { return rcpf(1.0f + __expf(-x)); }
__device__ __forceinline__ float tanhff(float x){ return 1.0f - 2.0f * rcpf(1.0f + __expf(2.0f * x)); }

__device__ __forceinline__ unsigned packf2(float lo, float hi) {
  _Float16 a = (_Float16)lo, b = (_Float16)hi;
  unsigned short ua = __builtin_bit_cast(unsigned short, a);
  unsigned short ub = __builtin_bit_cast(unsigned short, b);
  return (unsigned)ua | ((unsigned)ub << 16);
}

// A fragment: lane (q=lane>>4, j=lane&15) holds W[row=base+j][k0 .. k0+7].
// A and B share the k-chunk packing (permutation cancels); the C/D mapping
// (col=lane&15, row=4*(lane>>4)+reg) is the only load-bearing layout.
__device__ __forceinline__ f16x8 afrag(const float* __restrict__ W, int row,
                                       int k0, int ld) {
  const float4* p = reinterpret_cast<const float4*>(W + (size_t)row * ld + k0);
  const float4 u = p[0], v = p[1];
  f16x8 a;
  a[0] = (_Float16)u.x; a[1] = (_Float16)u.y; a[2] = (_Float16)u.z; a[3] = (_Float16)u.w;
  a[4] = (_Float16)v.x; a[5] = (_Float16)v.y; a[6] = (_Float16)v.z; a[7] = (_Float16)v.w;
  return a;
}

// Wave w owns M-tiles {w, 8+w, 16+w, 24+w} = gate rows {i,f,g,o} of cells
// [16w,16w+16). Same lane+reg then holds all 4 gates of one cell -> activation
// is fully in-register; ONE barrier per step (publish h to LDS).

// ---------------- K1: layer 1 ----------------
// 256 blocks x 512 thr (8 waves), chains b0,b0+1 (B cols 0,1; 2..15 pad).
__global__ __launch_bounds__(512) void lstm_l1(
    const float* __restrict__ x, const float* __restrict__ Wx1,
    const float* __restrict__ bx1, const float* __restrict__ Wh1,
    const float* __restrict__ bh1, _Float16* __restrict__ h1out)
{
  const int tid  = threadIdx.x;
  const int b0   = blockIdx.x * 2;
  const int w    = tid >> 6;           // wave 0..7
  const int lane = tid & 63;
  const int q    = lane >> 4;          // k-group AND D-row group
  const int n    = lane & 15;          // B/D col
  const int j0   = 16 * w + 4 * q;     // first cell this lane owns

  __shared__ __align__(16) _Float16 xF[8][16][8];      // [kc][col][e] 2 KiB
  __shared__ __align__(16) _Float16 h1B[2][2][16][8];  // [par][c][kc][e] 1 KiB
  __shared__ float xg2[16][516];                       // [col][row] 32.3 KiB

  f16x8 Ax[4][2], Ah[4][4];            // (8+16) frags = 96 VGPR
#pragma unroll
  for (int g = 0; g < 4; ++g) {
    const int row = g * 128 + 16 * w + n;
#pragma unroll
    for (int kt = 0; kt < 2; ++kt) Ax[g][kt] = afrag(Wx1, row, kt * 32 + q * 8, kI);
#pragma unroll
    for (int kt = 0; kt < 4; ++kt) Ah[g][kt] = afrag(Wh1, row, kt * 32 + q * 8, kH);
  }

  f32x4 bI4, bF4, bG4, bO4;
#pragma unroll
  for (int r = 0; r < 4; ++r) {
    bI4[r] = bx1[j0 + r]       + bh1[j0 + r];
    bF4[r] = bx1[j0 + 128 + r] + bh1[j0 + 128 + r];
    bG4[r] = bx1[j0 + 256 + r] + bh1[j0 + 256 + r];
    bO4[r] = bx1[j0 + 384 + r] + bh1[j0 + 384 + r];
  }
  if (tid < 256) reinterpret_cast<_Float16*>(&h1B[1][0][0][0])[tid] = (_Float16)0.f;

  f32x4 cst = {0.f, 0.f, 0.f, 0.f};
  const int csel = (n < 2) ? n : 0;
  const char* h1base = reinterpret_cast<const char*>(&h1B[0][0][0][0]);

  for (int t0 = 0; t0 < kS; t0 += 8) {
    {  // stage x tile (512 float2, coalesced)
      const int col = tid >> 5, k2 = tid & 31;   // col = dt*2+c
      const int c = col & 1, dt = col >> 1, k = k2 * 2;
      const float2 v = *reinterpret_cast<const float2*>(
          x + ((size_t)(b0 + c) * kS + (size_t)(t0 + dt)) * kI + k);
      *reinterpret_cast<unsigned*>(&xF[k >> 3][col][k & 7]) = packf2(v.x, v.y);
    }
    __syncthreads();

    // batched x-GEMM -> xg2[col][row]
    {
      const char* xb = reinterpret_cast<const char*>(&xF[0][0][0]);
      f32x4 e0 = {0,0,0,0}, e1 = {0,0,0,0}, e2 = {0,0,0,0}, e3 = {0,0,0,0};
#pragma unroll
      for (int kt = 0; kt < 2; ++kt) {
        const f16x8 bf = *reinterpret_cast<const f16x8*>(
            xb + (((kt * 4 + q) * 16 + n) << 4));
        e0 = MFMA16(Ax[0][kt], bf, e0);  e1 = MFMA16(Ax[1][kt], bf, e1);
        e2 = MFMA16(Ax[2][kt], bf, e2);  e3 = MFMA16(Ax[3][kt], bf, e3);
      }
      *reinterpret_cast<f32x4*>(&xg2[n][j0])       = e0;
      *reinterpret_cast<f32x4*>(&xg2[n][j0 + 128]) = e1;
      *reinterpret_cast<f32x4*>(&xg2[n][j0 + 256]) = e2;
      *reinterpret_cast<f32x4*>(&xg2[n][j0 + 384]) = e3;
    }
    __syncthreads();

    for (int dt = 0; dt < 8; ++dt) {
      const int t = t0 + dt;
      const char* hb = h1base + ((((t + 1) & 1) * 2 + csel) << 8);

      f32x4 d0 = {0,0,0,0}, d1 = {0,0,0,0}, d2 = {0,0,0,0}, d3 = {0,0,0,0};
#pragma unroll
      for (int kt = 0; kt < 4; ++kt) {
        const f16x8 bf = *reinterpret_cast<const f16x8*>(hb + ((kt * 4 + q) << 4));
        d0 = MFMA16(Ah[0][kt], bf, d0);  d1 = MFMA16(Ah[1][kt], bf, d1);
        d2 = MFMA16(Ah[2][kt], bf, d2);  d3 = MFMA16(Ah[3][kt], bf, d3);
      }

      if (n < 2) {     // in-register activation: this lane's 4 cells, chain n
        const int col = dt * 2 + n;
        const f32x4 xa  = *reinterpret_cast<const f32x4*>(&xg2[col][j0]);
        const f32x4 xf  = *reinterpret_cast<const f32x4*>(&xg2[col][j0 + 128]);
        const f32x4 xgg = *reinterpret_cast<const f32x4*>(&xg2[col][j0 + 256]);
        const f32x4 xo  = *reinterpret_cast<const f32x4*>(&xg2[col][j0 + 384]);
        float h[4];
#pragma unroll
        for (int r = 0; r < 4; ++r) {
          const float gi = d0[r] + xa[r]  + bI4[r];
          const float gf = d1[r] + xf[r]  + bF4[r];
          const float gg = d2[r] + xgg[r] + bG4[r];
          const float go = d3[r] + xo[r]  + bO4[r];
          cst[r] = sigf(gf) * cst[r] + sigf(gi) * tanhff(gg);
          h[r] = sigf(go) * tanhff(cst[r]);
        }
        uint2 hp;
        hp.x = packf2(h[0], h[1]);
        hp.y = packf2(h[2], h[3]);
        *reinterpret_cast<uint2*>(&h1B[t & 1][n][j0 >> 3][j0 & 7]) = hp;
        *reinterpret_cast<uint2*>(
            h1out + ((size_t)(b0 + n) * kS + (size_t)t) * kH + j0) = hp;
      }
      __syncthreads();
    }
  }
}

// ---------------- K2: layer 2 + head ----------------
__global__ __launch_bounds__(512) void lstm_l2(
    const _Float16* __restrict__ h1in,
    const float* __restrict__ Wx2, const float* __restrict__ bx2,
    const float* __restrict__ Wh2, const float* __restrict__ bh2,
    const float* __restrict__ Wc,  const float* __restrict__ bc,
    float* __restrict__ out)
{
  const int tid  = threadIdx.x;
  const int b0   = blockIdx.x * 2;
  const int w    = tid >> 6;
  const int lane = tid & 63;
  const int q    = lane >> 4;
  const int n    = lane & 15;
  const int j0   = 16 * w + 4 * q;

  __shared__ __align__(16) _Float16 h1F[16][16][8];    // [kc][col][e] 4 KiB
  __shared__ __align__(16) _Float16 h2B[2][2][16][8];  // 1 KiB
  __shared__ float xg2[16][516];                       // 32.3 KiB
  __shared__ float hfin[2][128];

  f16x8 Ax[4][4], Ah[4][4];            // 32 frags = 128 VGPR
#pragma unroll
  for (int g = 0; g < 4; ++g) {
    const int row = g * 128 + 16 * w + n;
#pragma unroll
    for (int kt = 0; kt < 4; ++kt) {
      Ax[g][kt] = afrag(Wx2, row, kt * 32 + q * 8, kH);
      Ah[g][kt] = afrag(Wh2, row, kt * 32 + q * 8, kH);
    }
  }

  f32x4 bI4, bF4, bG4, bO4;
#pragma unroll
  for (int r = 0; r < 4; ++r) {
    bI4[r] = bx2[j0 + r]       + bh2[j0 + r];
    bF4[r] = bx2[j0 + 128 + r] + bh2[j0 + 128 + r];
    bG4[r] = bx2[j0 + 256 + r] + bh2[j0 + 256 + r];
    bO4[r] = bx2[j0 + 384 + r] + bh2[j0 + 384 + r];
  }
  if (tid < 256) reinterpret_cast<_Float16*>(&h2B[1][0][0][0])[tid] = (_Float16)0.f;

  f32x4 cst = {0.f, 0.f, 0.f, 0.f};
  const int csel = (n < 2) ? n : 0;
  const char* h2base = reinterpret_cast<const char*>(&h2B[0][0][0][0]);

  for (int t0 = 0; t0 < kS; t0 += 8) {
    {  // stage h1 tile (512 x 8B, coalesced)
      const int col = tid >> 5, quad = tid & 31;   // col = dt*2+c, k = quad*4
      const int c = col & 1, dt = col >> 1, k = quad * 4;
      const uint2 v = *reinterpret_cast<const uint2*>(
          h1in + ((size_t)(b0 + c) * kS + (size_t)(t0 + dt)) * kH + k);
      *reinterpret_cast<uint2*>(&h1F[k >> 3][col][k & 7]) = v;
    }
    __syncthreads();

    // batched GEMM: Wx2 . h1 -> xg2[col][row]
    {
      const char* xb = reinterpret_cast<const char*>(&h1F[0][0][0]);
      f32x4 e0 = {0,0,0,0}, e1 = {0,0,0,0}, e2 = {0,0,0,0}, e3 = {0,0,0,0};
#pragma unroll
      for (int kt = 0; kt < 4; ++kt) {
        const f16x8 bf = *reinterpret_cast<const f16x8*>(
            xb + (((kt * 4 + q) * 16 + n) << 4));
        e0 = MFMA16(Ax[0][kt], bf, e0);  e1 = MFMA16(Ax[1][kt], bf, e1);
        e2 = MFMA16(Ax[2][kt], bf, e2);  e3 = MFMA16(Ax[3][kt], bf, e3);
      }
      *reinterpret_cast<f32x4*>(&xg2[n][j0])       = e0;
      *reinterpret_cast<f32x4*>(&xg2[n][j0 + 128]) = e1;
      *reinterpret_cast<f32x4*>(&xg2[n][j0 + 256]) = e2;
      *reinterpret_cast<f32x4*>(&xg2[n][j0 + 384]) = e3;
    }
    __syncthreads();

    for (int dt = 0; dt < 8; ++dt) {
      const int t = t0 + dt;
      const char* hb = h2base + ((((t + 1) & 1) * 2 + csel) << 8);

      f32x4 d0 = {0,0,0,0}, d1 = {0,0,0,0}, d2 = {0,0,0,0}, d3 = {0,0,0,0};
#pragma unroll
      for (int kt = 0; kt < 4; ++kt) {
        const f16x8 bf = *reinterpret_cast<const f16x8*>(hb + ((kt * 4 + q) << 4));
        d0 = MFMA16(Ah[0][kt], bf, d0);  d1 = MFMA16(Ah[1][kt], bf, d1);
        d2 = MFMA16(Ah[2][kt], bf, d2);  d3 = MFMA16(Ah[3][kt], bf, d3);
      }

      if (n < 2) {
        const int col = dt * 2 + n;
        const f32x4 xa  = *reinterpret_cast<const f32x4*>(&xg2[col][j0]);
        const f32x4 xf  = *reinterpret_cast<const f32x4*>(&xg2[col][j0 + 128]);
        const f32x4 xgg = *reinterpret_cast<const f32x4*>(&xg2[col][j0 + 256]);
        const f32x4 xo  = *reinterpret_cast<const f32x4*>(&xg2[col][j0 + 384]);
        float h[4];
#pragma unroll
        for (int r = 0; r < 4; ++r) {
          const float gi = d0[r] + xa[r]  + bI4[r];
          const float gf = d1[r] + xf[r]  + bF4[r];
          const float gg = d2[r] + xgg[r] + bG4[r];
          const float go = d3[r] + xo[r]  + bO4[r];
          cst[r] = sigf(gf) * cst[r] + sigf(gi) * tanhff(gg);
          h[r] = sigf(go) * tanhff(cst[r]);
        }
        uint2 hp;
        hp.x = packf2(h[0], h[1]);
        hp.y = packf2(h[2], h[3]);
        *reinterpret_cast<uint2*>(&h2B[t & 1][n][j0 >> 3][j0 & 7]) = hp;
        if (t == kS - 1) {
          f32x4 hv = {h[0], h[1], h[2], h[3]};
          *reinterpret_cast<f32x4*>(&hfin[n][j0]) = hv;
        }
      }
      __syncthreads();
    }
  }

  // classifier head: logits[b0+c, m] = Wc[m,:] . h2fin[c] + bc[m]
  if (tid < 8) {
    const int m = tid & 3, c = tid >> 2;
    const float* wr = Wc + (size_t)m * kH;
    float s0 = 0.f, s1 = 0.f, s2 = 0.f, s3 = 0.f;
#pragma unroll
    for (int j = 0; j < kH; j += 4) {
      s0 = fmaf(wr[j],     hfin[c][j],     s0);
      s1 = fmaf(wr[j + 1], hfin[c][j + 1], s1);
      s2 = fmaf(wr[j + 2], hfin[c][j + 2], s2);
      s3 = fmaf(wr[j + 3], hfin[c][j + 3], s3);
    }
    out[(size_t)(b0 + c) * 4 + m] = bc[m] + ((s0 + s1) + (s2 + s3));
  }
}

} // namespace

extern "C" void kernel_launch(void* const* d_in, const int* in_sizes, int n_in,
                              void* d_out, int out_size, void* d_ws, size_t ws_size,
                              hipStream_t stream) {
  const float* x   = (const float*)d_in[0];
  const float* Wx1 = (const float*)d_in[1];
  const float* bx1 = (const float*)d_in[2];
  const float* Wh1 = (const float*)d_in[3];
  const float* bh1 = (const float*)d_in[4];
  const float* Wx2 = (const float*)d_in[5];
  const float* bx2 = (const float*)d_in[6];
  const float* Wh2 = (const float*)d_in[7];
  const float* bh2 = (const float*)d_in[8];
  const float* Wc  = (const float*)d_in[9];
  const float* bc  = (const float*)d_in[10];

  _Float16* h1 = (_Float16*)d_ws;   // 512*1024*128 fp16 = 128 MiB layer-1 stream

  hipLaunchKernelGGL(lstm_l1, dim3(256), dim3(512), 0, stream,
                     x, Wx1, bx1, Wh1, bh1, h1);
  hipLaunchKernelGGL(lstm_l2, dim3(256), dim3(512), 0, stream,
                     h1, Wx2, bx2, Wh2, bh2, Wc, bc, (float*)d_out);
}